// Round 2
// baseline (198.432 us; speedup 1.0000x reference)
//
#include <hip/hip_runtime.h>

#define IMG 65536   // 256*256
#define W 256
#define H 256

// d_ws layout: ktab = 20 rows x 256 floats (zero-padded composed kernels, tap j at [8+j])
//              ord  = 192 ints at byte offset 20480 (images sorted by t desc)

__global__ __launch_bounds__(256) void init_kernel(const int* __restrict__ t,
                                                   float* __restrict__ ktab,
                                                   int* __restrict__ ord) {
  __shared__ double cur[256];
  __shared__ double base[11];
  __shared__ int keys[192];
  int tid = threadIdx.x;
  if (tid == 0) {
    double p[11];
    double s = 0.0;
    for (int i = 0; i < 11; ++i) {
      double xx = (double)(i - 5) * 0.5;       // x / SIGMA, SIGMA=2
      p[i] = exp(-0.5 * xx * xx);
      s += p[i];
    }
    for (int i = 0; i < 11; ++i) base[i] = (double)(float)(p[i] / s);  // match np float32 taps
  }
  // row 0: identity kernel (t=0 safety)
  ktab[tid] = (tid == 8) ? 1.0f : 0.0f;
  __syncthreads();
  cur[tid] = (tid < 11) ? base[tid] : 0.0;
  __syncthreads();
  ktab[256 + tid] = (tid >= 8 && tid <= 18) ? (float)cur[tid - 8] : 0.0f;
  for (int tt = 2; tt <= 19; ++tt) {
    int Lprev = 10 * (tt - 1) + 1;
    double a = 0.0;
    for (int i = 0; i < 11; ++i) {
      int jj = tid - i;
      if (jj >= 0 && jj < Lprev) a += base[i] * cur[jj];
    }
    __syncthreads();
    cur[tid] = a;
    __syncthreads();
    ktab[tt * 256 + tid] = (tid >= 8 && tid <= 8 + 10 * tt) ? (float)cur[tid - 8] : 0.0f;
  }
  // rank-sort 192 (b,c) images by t descending (stable) for load balance
  if (tid < 192) keys[tid] = min(max(t[tid / 3], 0), 19);
  __syncthreads();
  if (tid < 192) {
    int k = keys[tid];
    int rank = 0;
    for (int j = 0; j < 192; ++j) {
      int kj = keys[j];
      if (kj > k || (kj == k && j < tid)) ++rank;
    }
    ord[rank] = tid;
  }
}

// H-pass: conv along h. Block = (w-tile 64 wide) x (full 256 rows) of one image.
__global__ __launch_bounds__(256) void hpass_kernel(const float* __restrict__ x,
                                                    const int* __restrict__ t,
                                                    const float* __restrict__ ktab,
                                                    const int* __restrict__ ord,
                                                    float* __restrict__ out) {
  __shared__ float tile[H][64];
  int tid = threadIdx.x;
  int img = ord[blockIdx.y];
  int wt = blockIdx.x;
  int b = img / 3;
  int tv = min(max(t[b], 0), 19);
  int R = 5 * tv;
  int L = 10 * tv + 1;
  const float* __restrict__ kt = ktab + tv * 256;  // wave-uniform -> s_load taps
  const float* src = x + (size_t)img * IMG + (wt << 6);
  float* dst = out + (size_t)img * IMG + (wt << 6);
  {
    int c4 = (tid & 15) << 2;
    int r0 = tid >> 4;
    for (int r = r0; r < H; r += 16) {
      float4 v = *reinterpret_cast<const float4*>(src + r * W + c4);
      *reinterpret_cast<float4*>(&tile[r][c4]) = v;
    }
  }
  __syncthreads();
  int lane = tid & 63;
  int wv = tid >> 6;
  int nIter = (L + 14) & ~7;   // round L+7 up to multiple of 8; extra taps are zeros
  for (int g = 0; g < 8; ++g) {
    int h0 = (wv << 6) + (g << 3);
    float acc[8] = {0.f, 0.f, 0.f, 0.f, 0.f, 0.f, 0.f, 0.f};
    float kq[8] = {0.f, 0.f, 0.f, 0.f, 0.f, 0.f, 0.f, 0.f};
    int pbase = h0 - R;
    for (int jb = 0; jb < nIter; jb += 8) {
#pragma unroll
      for (int u = 0; u < 8; ++u) {
        int j = jb + u;
        kq[u] = kt[j + 8];
        int p = pbase + j;
        int rp = 255 - abs(255 - abs(p));   // reflect (single fold valid: R<=95)
        float v = tile[rp][lane];
#pragma unroll
        for (int o = 0; o < 8; ++o) acc[o] += kq[(u - o) & 7] * v;  // static idx after unroll
      }
    }
#pragma unroll
    for (int o = 0; o < 8; ++o) dst[(h0 + o) * W + lane] = acc[o];
  }
}

// W-pass: conv along w, in-place on out. Block = (64-row band) x (full 256 cols).
// LDS XOR-swizzled so lane=row reads (stride 256 words) are bank-conflict-free.
__global__ __launch_bounds__(256) void wpass_kernel(const int* __restrict__ t,
                                                    const float* __restrict__ ktab,
                                                    const int* __restrict__ ord,
                                                    float* __restrict__ io) {
  __shared__ float tile[64 * 256];
  int tid = threadIdx.x;
  int img = ord[blockIdx.y];
  int ht = blockIdx.x;
  int b = img / 3;
  int tv = min(max(t[b], 0), 19);
  int R = 5 * tv;
  int L = 10 * tv + 1;
  const float* __restrict__ kt = ktab + tv * 256;
  float* base = io + (size_t)img * IMG + (ht << 6) * W;
  int lane = tid & 63;
  int wv = tid >> 6;
  // load 64 rows x 256 cols; lane strided by 64 in w so swizzled LDS writes are conflict-free
  for (int i = 0; i < 16; ++i) {
    int r = (wv << 4) + i;
    int rsw = r & 31;
#pragma unroll
    for (int k = 0; k < 4; ++k) {
      int c = lane + (k << 6);
      tile[(r << 8) + (c ^ rsw)] = base[r * W + c];
    }
  }
  __syncthreads();
  int rowbase = lane << 8;
  int sw = lane & 31;
  int nIter = (L + 14) & ~7;
  for (int g = 0; g < 8; ++g) {
    int w0 = (wv << 6) + (g << 3);
    float acc[8] = {0.f, 0.f, 0.f, 0.f, 0.f, 0.f, 0.f, 0.f};
    float kq[8] = {0.f, 0.f, 0.f, 0.f, 0.f, 0.f, 0.f, 0.f};
    int pbase = w0 - R;
    for (int jb = 0; jb < nIter; jb += 8) {
#pragma unroll
      for (int u = 0; u < 8; ++u) {
        int j = jb + u;
        kq[u] = kt[j + 8];
        int p = pbase + j;
        int rp = 255 - abs(255 - abs(p));
        float v = tile[rowbase + (rp ^ sw)];
#pragma unroll
        for (int o = 0; o < 8; ++o) acc[o] += kq[(u - o) & 7] * v;
      }
    }
    float4 v0 = make_float4(acc[0], acc[1], acc[2], acc[3]);
    float4 v1 = make_float4(acc[4], acc[5], acc[6], acc[7]);
    *reinterpret_cast<float4*>(base + lane * W + w0) = v0;
    *reinterpret_cast<float4*>(base + lane * W + w0 + 4) = v1;
  }
}

extern "C" void kernel_launch(void* const* d_in, const int* in_sizes, int n_in,
                              void* d_out, int out_size, void* d_ws, size_t ws_size,
                              hipStream_t stream) {
  const float* x = (const float*)d_in[0];
  const int* t = (const int*)d_in[1];
  float* out = (float*)d_out;
  float* ktab = (float*)d_ws;
  int* ord = (int*)((char*)d_ws + 20480);

  hipLaunchKernelGGL(init_kernel, dim3(1), dim3(256), 0, stream, t, ktab, ord);
  hipLaunchKernelGGL(hpass_kernel, dim3(4, 192), dim3(256), 0, stream, x, t, ktab, ord, out);
  hipLaunchKernelGGL(wpass_kernel, dim3(4, 192), dim3(256), 0, stream, t, ktab, ord, out);
}

// Round 3
// 180.073 us; speedup vs baseline: 1.1020x; 1.1020x over previous
//
#include <hip/hip_runtime.h>

#define IMG 65536   // 256*256
#define W 256
#define H 256

// d_ws layout:
//   ktab: 20 x 256 floats (truncated, renormalized composed kernels; tap j at [8+j]), bytes [0, 20480)
//   ord : 192 ints at byte 20480 (images sorted by t desc)
//   rtab: 20 ints at byte 21248 (truncated radius per t)

__global__ __launch_bounds__(256) void init_kernel(const int* __restrict__ t,
                                                   float* __restrict__ ktab,
                                                   int* __restrict__ ord,
                                                   int* __restrict__ rtab) {
  __shared__ double cur[256];
  __shared__ double base[11];
  __shared__ int keys[192];
  __shared__ int sR;
  __shared__ double sScale;
  int tid = threadIdx.x;
  if (tid == 0) {
    double p[11];
    double s = 0.0;
    for (int i = 0; i < 11; ++i) {
      double xx = (double)(i - 5) * 0.5;       // x / SIGMA, SIGMA=2
      p[i] = exp(-0.5 * xx * xx);
      s += p[i];
    }
    for (int i = 0; i < 11; ++i) base[i] = (double)(float)(p[i] / s);  // match np float32 taps
    rtab[0] = 0;
  }
  // row 0: identity kernel (t=0 safety)
  ktab[tid] = (tid == 8) ? 1.0f : 0.0f;
  __syncthreads();
  cur[tid] = (tid < 11) ? base[tid] : 0.0;
  __syncthreads();
  for (int tt = 1; tt <= 19; ++tt) {
    if (tt > 1) {
      int Lprev = 10 * (tt - 1) + 1;
      double a = 0.0;
      for (int i = 0; i < 11; ++i) {
        int jj = tid - i;
        if (jj >= 0 && jj < Lprev) a += base[i] * cur[jj];
      }
      __syncthreads();
      cur[tid] = a;
      __syncthreads();
    }
    if (tid == 0) {
      int c = 5 * tt;
      int Rk = 5 * tt;
      double drop = 0.0;
      while (Rk > 1) {                       // truncate: drop outer taps while mass < 1e-5
        double d2 = drop + cur[c - Rk] + cur[c + Rk];
        if (d2 > 1e-5) break;
        drop = d2;
        --Rk;
      }
      double ksum = 0.0;
      for (int j = c - Rk; j <= c + Rk; ++j) ksum += cur[j];
      sR = Rk;
      sScale = 1.0 / ksum;                   // renormalize kept mass to 1
      rtab[tt] = Rk;
    }
    __syncthreads();
    int Rk = sR;
    int c0 = 5 * tt - Rk;
    int Lk = 2 * Rk + 1;
    ktab[tt * 256 + tid] =
        (tid >= 8 && tid < 8 + Lk) ? (float)(cur[tid - 8 + c0] * sScale) : 0.0f;
    __syncthreads();
  }
  // rank-sort 192 (b,c) images by t descending (stable) for load balance
  if (tid < 192) keys[tid] = min(max(t[tid / 3], 0), 19);
  __syncthreads();
  if (tid < 192) {
    int k = keys[tid];
    int rank = 0;
    for (int j = 0; j < 192; ++j) {
      int kj = keys[j];
      if (kj > k || (kj == k && j < tid)) ++rank;
    }
    ord[rank] = tid;
  }
}

// H-pass: conv along h. Block = (32-wide w-tile) x (full 256 rows) of one image.
// LDS tile[256][32] = 32 KB. Each thread: 2 groups of 16 consecutive output rows,
// 16-deep rolling tap window. Interior tap-blocks skip reflect math entirely.
__global__ __launch_bounds__(256, 4) void hpass_kernel(const float* __restrict__ x,
                                                       const int* __restrict__ t,
                                                       const float* __restrict__ ktab,
                                                       const int* __restrict__ ord,
                                                       const int* __restrict__ rtab,
                                                       float* __restrict__ out) {
  __shared__ float tile[H][32];
  int tid = threadIdx.x;
  int img = ord[blockIdx.y];
  int wt = blockIdx.x;                        // 0..7
  int b = img / 3;
  int tv = min(max(t[b], 0), 19);
  int R = rtab[tv];
  int L = 2 * R + 1;
  const float* __restrict__ kt = ktab + tv * 256;   // wave-uniform -> s_load taps
  const float* src = x + (size_t)img * IMG + (wt << 5);
  float* dst = out + (size_t)img * IMG + (wt << 5);
  {
    int c4 = (tid & 7) << 2;
    int r0 = tid >> 3;                        // 0..31
    for (int r = r0; r < H; r += 32) {
      float4 v = *reinterpret_cast<const float4*>(src + r * W + c4);
      *reinterpret_cast<float4*>(&tile[r][c4]) = v;
    }
  }
  __syncthreads();
  int col = tid & 31;
  int rgrp = tid >> 5;                        // 0..7
  int nIter = (L + 30) & ~15;                 // >= L+15, multiple of 16; extra taps are zeros
  for (int g = 0; g < 2; ++g) {
    int h0 = (rgrp << 5) + (g << 4);
    float acc[16];
    float kq[16];
#pragma unroll
    for (int o = 0; o < 16; ++o) { acc[o] = 0.f; kq[o] = 0.f; }
    int pbase = h0 - R;
    for (int jb = 0; jb < nIter; jb += 16) {
      int p0 = pbase + jb;
      if (p0 >= 0 && p0 <= 240) {
        // interior fast path: sequential LDS addresses (offset immediates)
#pragma unroll
        for (int u = 0; u < 16; ++u) {
          kq[u] = kt[jb + u + 8];
          float v = tile[p0 + u][col];
#pragma unroll
          for (int o = 0; o < 16; ++o) acc[o] += kq[(u - o) & 15] * v;
        }
      } else {
#pragma unroll
        for (int u = 0; u < 16; ++u) {
          kq[u] = kt[jb + u + 8];
          int p = p0 + u;
          int rp = 255 - abs(255 - abs(p));   // reflect (single fold valid: |p| <= 510)
          float v = tile[rp][col];
#pragma unroll
          for (int o = 0; o < 16; ++o) acc[o] += kq[(u - o) & 15] * v;
        }
      }
    }
#pragma unroll
    for (int o = 0; o < 16; ++o) dst[(h0 + o) * W + col] = acc[o];
  }
}

// W-pass: conv along w, in-place on out. Block = (32-row band) x (full 256 cols).
// LDS tile[32][256] word-XOR-swizzled so lane=row reads (stride 1 KB) are conflict-free.
__global__ __launch_bounds__(256, 4) void wpass_kernel(const int* __restrict__ t,
                                                       const float* __restrict__ ktab,
                                                       const int* __restrict__ ord,
                                                       const int* __restrict__ rtab,
                                                       float* __restrict__ io) {
  __shared__ float tile[32 * 256];
  int tid = threadIdx.x;
  int img = ord[blockIdx.y];
  int ht = blockIdx.x;                        // 0..7
  int b = img / 3;
  int tv = min(max(t[b], 0), 19);
  int R = rtab[tv];
  int L = 2 * R + 1;
  const float* __restrict__ kt = ktab + tv * 256;
  float* base = io + (size_t)img * IMG + (ht << 5) * W;
  {
    int r = tid >> 3;                         // 0..31
    int c4 = (tid & 7) << 2;
    int sw = r;                               // word-granular swizzle key
    for (int kk = 0; kk < 8; ++kk) {
      int c = c4 + (kk << 5);
      float4 v = *reinterpret_cast<const float4*>(base + r * W + c);
      tile[(r << 8) + ((c + 0) ^ sw)] = v.x;
      tile[(r << 8) + ((c + 1) ^ sw)] = v.y;
      tile[(r << 8) + ((c + 2) ^ sw)] = v.z;
      tile[(r << 8) + ((c + 3) ^ sw)] = v.w;
    }
  }
  __syncthreads();
  int row = tid & 31;
  int wgrp = tid >> 5;                        // 0..7
  int rowbase = row << 8;
  int sw = row;
  int nIter = (L + 30) & ~15;
  for (int g = 0; g < 2; ++g) {
    int w0 = (wgrp << 5) + (g << 4);
    float acc[16];
    float kq[16];
#pragma unroll
    for (int o = 0; o < 16; ++o) { acc[o] = 0.f; kq[o] = 0.f; }
    int pbase = w0 - R;
    for (int jb = 0; jb < nIter; jb += 16) {
      int p0 = pbase + jb;
      if (p0 >= 0 && p0 <= 240) {
#pragma unroll
        for (int u = 0; u < 16; ++u) {
          kq[u] = kt[jb + u + 8];
          float v = tile[rowbase + ((p0 + u) ^ sw)];
#pragma unroll
          for (int o = 0; o < 16; ++o) acc[o] += kq[(u - o) & 15] * v;
        }
      } else {
#pragma unroll
        for (int u = 0; u < 16; ++u) {
          kq[u] = kt[jb + u + 8];
          int p = p0 + u;
          int rp = 255 - abs(255 - abs(p));
          float v = tile[rowbase + (rp ^ sw)];
#pragma unroll
          for (int o = 0; o < 16; ++o) acc[o] += kq[(u - o) & 15] * v;
        }
      }
    }
    float4 v0 = make_float4(acc[0], acc[1], acc[2], acc[3]);
    float4 v1 = make_float4(acc[4], acc[5], acc[6], acc[7]);
    float4 v2 = make_float4(acc[8], acc[9], acc[10], acc[11]);
    float4 v3 = make_float4(acc[12], acc[13], acc[14], acc[15]);
    float* o0 = base + row * W + w0;
    *reinterpret_cast<float4*>(o0 + 0) = v0;
    *reinterpret_cast<float4*>(o0 + 4) = v1;
    *reinterpret_cast<float4*>(o0 + 8) = v2;
    *reinterpret_cast<float4*>(o0 + 12) = v3;
  }
}

extern "C" void kernel_launch(void* const* d_in, const int* in_sizes, int n_in,
                              void* d_out, int out_size, void* d_ws, size_t ws_size,
                              hipStream_t stream) {
  const float* x = (const float*)d_in[0];
  const int* t = (const int*)d_in[1];
  float* out = (float*)d_out;
  float* ktab = (float*)d_ws;
  int* ord = (int*)((char*)d_ws + 20480);
  int* rtab = (int*)((char*)d_ws + 21248);

  hipLaunchKernelGGL(init_kernel, dim3(1), dim3(256), 0, stream, t, ktab, ord, rtab);
  hipLaunchKernelGGL(hpass_kernel, dim3(8, 192), dim3(256), 0, stream, x, t, ktab, ord, rtab, out);
  hipLaunchKernelGGL(wpass_kernel, dim3(8, 192), dim3(256), 0, stream, t, ktab, ord, rtab, out);
}

// Round 5
// 138.669 us; speedup vs baseline: 1.4310x; 1.2986x over previous
//
#include <hip/hip_runtime.h>

#define IMG 65536   // 256*256
#define W 256
#define H 256

// d_ws layout:
//   ktab: 20 x 256 floats (truncated, renormalized composed kernels; tap j at [8+j]), bytes [0, 20480)
//   ord : 192 ints at byte 20480 (images sorted by t desc)
//   rtab: 20 ints at byte 21248 (truncated radius per t)

__global__ __launch_bounds__(256) void init_kernel(const int* __restrict__ t,
                                                   float* __restrict__ ktab,
                                                   int* __restrict__ ord,
                                                   int* __restrict__ rtab) {
  __shared__ double cur[256];
  __shared__ double sc[256];    // prefix-sum scratch
  __shared__ double base[11];
  __shared__ int keys[192];
  __shared__ int sRmax;
  int tid = threadIdx.x;
  if (tid == 0) {
    double p[11];
    double s = 0.0;
    for (int i = 0; i < 11; ++i) {
      double xx = (double)(i - 5) * 0.5;       // x / SIGMA, SIGMA=2
      p[i] = exp(-0.5 * xx * xx);
      s += p[i];
    }
    for (int i = 0; i < 11; ++i) base[i] = (double)(float)(p[i] / s);  // match np float32 taps
    rtab[0] = 0;
  }
  // row 0: identity kernel (t=0 safety)
  ktab[tid] = (tid == 8) ? 1.0f : 0.0f;
  __syncthreads();
  cur[tid] = (tid < 11) ? base[tid] : 0.0;
  __syncthreads();
  for (int tt = 1; tt <= 19; ++tt) {
    if (tt > 1) {
      int Lprev = 10 * (tt - 1) + 1;
      double a = 0.0;
      for (int i = 0; i < 11; ++i) {
        int jj = tid - i;
        if (jj >= 0 && jj < Lprev) a += base[i] * cur[jj];
      }
      __syncthreads();
      cur[tid] = a;
      __syncthreads();
    }
    // parallel inclusive prefix sum of cur -> sc (Hillis-Steele, 8 steps)
    sc[tid] = cur[tid];
    __syncthreads();
#pragma unroll
    for (int off = 1; off < 256; off <<= 1) {
      double tmp = (tid >= off) ? sc[tid - off] : 0.0;
      __syncthreads();
      sc[tid] += tmp;
      __syncthreads();
    }
    if (tid == 0) sRmax = 1;
    __syncthreads();
    // truncation: R = max r in [1,5t] with tail-outside-(r-1) > 1e-5  (monotone)
    int c = 5 * tt;
    double total = sc[255];
    int r = tid;
    if (r >= 1 && r <= c) {
      double Srm1 = sc[c + r - 1] - sc[c - r];       // window sum, radius r-1
      if (total - Srm1 > 1e-5) atomicMax(&sRmax, r);
    }
    __syncthreads();
    int Rk = sRmax;
    double ksum = sc[c + Rk] - ((c - Rk - 1 >= 0) ? sc[c - Rk - 1] : 0.0);
    double scale = 1.0 / ksum;                       // renormalize kept mass to 1
    if (tid == 0) rtab[tt] = Rk;
    int c0 = c - Rk;
    int Lk = 2 * Rk + 1;
    ktab[tt * 256 + tid] =
        (tid >= 8 && tid < 8 + Lk) ? (float)(cur[tid - 8 + c0] * scale) : 0.0f;
    __syncthreads();
  }
  // rank-sort 192 (b,c) images by t descending (stable) for load balance
  if (tid < 192) keys[tid] = min(max(t[tid / 3], 0), 19);
  __syncthreads();
  if (tid < 192) {
    int k = keys[tid];
    int rank = 0;
    for (int j = 0; j < 192; ++j) {
      int kj = keys[j];
      if (kj > k || (kj == k && j < tid)) ++rank;
    }
    ord[rank] = tid;
  }
}

// H-pass: conv along h. Block = (32-wide w-tile) x (full 256 rows) of one image.
// LDS tile[256][32] = 32 KB. Each thread: 2 groups of 16 consecutive output rows,
// 16-deep rolling tap window. Interior tap-blocks skip reflect math entirely.
__global__ __launch_bounds__(256, 4) void hpass_kernel(const float* __restrict__ x,
                                                       const int* __restrict__ t,
                                                       const float* __restrict__ ktab,
                                                       const int* __restrict__ ord,
                                                       const int* __restrict__ rtab,
                                                       float* __restrict__ out) {
  __shared__ float tile[H][32];
  int tid = threadIdx.x;
  int img = ord[blockIdx.y];
  int wt = blockIdx.x;                        // 0..7
  int b = img / 3;
  int tv = min(max(t[b], 0), 19);
  int R = rtab[tv];
  int L = 2 * R + 1;
  const float* __restrict__ kt = ktab + tv * 256;   // wave-uniform -> s_load taps
  const float* src = x + (size_t)img * IMG + (wt << 5);
  float* dst = out + (size_t)img * IMG + (wt << 5);
  {
    int c4 = (tid & 7) << 2;
    int r0 = tid >> 3;                        // 0..31
    for (int r = r0; r < H; r += 32) {
      float4 v = *reinterpret_cast<const float4*>(src + r * W + c4);
      *reinterpret_cast<float4*>(&tile[r][c4]) = v;
    }
  }
  __syncthreads();
  int col = tid & 31;
  int rgrp = tid >> 5;                        // 0..7
  int nIter = (L + 30) & ~15;                 // >= L+15, multiple of 16; extra taps are zeros
  for (int g = 0; g < 2; ++g) {
    int h0 = (rgrp << 5) + (g << 4);
    float acc[16];
    float kq[16];
#pragma unroll
    for (int o = 0; o < 16; ++o) { acc[o] = 0.f; kq[o] = 0.f; }
    int pbase = h0 - R;
    for (int jb = 0; jb < nIter; jb += 16) {
      int p0 = pbase + jb;
      if (p0 >= 0 && p0 <= 240) {
        // interior fast path: sequential LDS addresses (offset immediates)
#pragma unroll
        for (int u = 0; u < 16; ++u) {
          kq[u] = kt[jb + u + 8];
          float v = tile[p0 + u][col];
#pragma unroll
          for (int o = 0; o < 16; ++o) acc[o] += kq[(u - o) & 15] * v;
        }
      } else {
#pragma unroll
        for (int u = 0; u < 16; ++u) {
          kq[u] = kt[jb + u + 8];
          int p = p0 + u;
          int rp = 255 - abs(255 - abs(p));   // reflect (single fold valid: |p| <= 510)
          float v = tile[rp][col];
#pragma unroll
          for (int o = 0; o < 16; ++o) acc[o] += kq[(u - o) & 15] * v;
        }
      }
    }
#pragma unroll
    for (int o = 0; o < 16; ++o) dst[(h0 + o) * W + col] = acc[o];
  }
}

// W-pass: conv along w, in-place on out. Block = (32-row band) x (full 256 cols).
// LDS tile[32][256] word-XOR-swizzled so lane=row reads (stride 1 KB) are conflict-free.
__global__ __launch_bounds__(256, 4) void wpass_kernel(const int* __restrict__ t,
                                                       const float* __restrict__ ktab,
                                                       const int* __restrict__ ord,
                                                       const int* __restrict__ rtab,
                                                       float* __restrict__ io) {
  __shared__ float tile[32 * 256];
  int tid = threadIdx.x;
  int img = ord[blockIdx.y];
  int ht = blockIdx.x;                        // 0..7
  int b = img / 3;
  int tv = min(max(t[b], 0), 19);
  int R = rtab[tv];
  int L = 2 * R + 1;
  const float* __restrict__ kt = ktab + tv * 256;
  float* base = io + (size_t)img * IMG + (ht << 5) * W;
  {
    int r = tid >> 3;                         // 0..31
    int c4 = (tid & 7) << 2;
    int sw = r;                               // word-granular swizzle key
    for (int kk = 0; kk < 8; ++kk) {
      int c = c4 + (kk << 5);
      float4 v = *reinterpret_cast<const float4*>(base + r * W + c);
      tile[(r << 8) + ((c + 0) ^ sw)] = v.x;
      tile[(r << 8) + ((c + 1) ^ sw)] = v.y;
      tile[(r << 8) + ((c + 2) ^ sw)] = v.z;
      tile[(r << 8) + ((c + 3) ^ sw)] = v.w;
    }
  }
  __syncthreads();
  int row = tid & 31;
  int wgrp = tid >> 5;                        // 0..7
  int rowbase = row << 8;
  int sw = row;
  int nIter = (L + 30) & ~15;
  for (int g = 0; g < 2; ++g) {
    int w0 = (wgrp << 5) + (g << 4);
    float acc[16];
    float kq[16];
#pragma unroll
    for (int o = 0; o < 16; ++o) { acc[o] = 0.f; kq[o] = 0.f; }
    int pbase = w0 - R;
    for (int jb = 0; jb < nIter; jb += 16) {
      int p0 = pbase + jb;
      if (p0 >= 0 && p0 <= 240) {
#pragma unroll
        for (int u = 0; u < 16; ++u) {
          kq[u] = kt[jb + u + 8];
          float v = tile[rowbase + ((p0 + u) ^ sw)];
#pragma unroll
          for (int o = 0; o < 16; ++o) acc[o] += kq[(u - o) & 15] * v;
        }
      } else {
#pragma unroll
        for (int u = 0; u < 16; ++u) {
          kq[u] = kt[jb + u + 8];
          int p = p0 + u;
          int rp = 255 - abs(255 - abs(p));
          float v = tile[rowbase + (rp ^ sw)];
#pragma unroll
          for (int o = 0; o < 16; ++o) acc[o] += kq[(u - o) & 15] * v;
        }
      }
    }
    float4 v0 = make_float4(acc[0], acc[1], acc[2], acc[3]);
    float4 v1 = make_float4(acc[4], acc[5], acc[6], acc[7]);
    float4 v2 = make_float4(acc[8], acc[9], acc[10], acc[11]);
    float4 v3 = make_float4(acc[12], acc[13], acc[14], acc[15]);
    float* o0 = base + row * W + w0;
    *reinterpret_cast<float4*>(o0 + 0) = v0;
    *reinterpret_cast<float4*>(o0 + 4) = v1;
    *reinterpret_cast<float4*>(o0 + 8) = v2;
    *reinterpret_cast<float4*>(o0 + 12) = v3;
  }
}

extern "C" void kernel_launch(void* const* d_in, const int* in_sizes, int n_in,
                              void* d_out, int out_size, void* d_ws, size_t ws_size,
                              hipStream_t stream) {
  const float* x = (const float*)d_in[0];
  const int* t = (const int*)d_in[1];
  float* out = (float*)d_out;
  float* ktab = (float*)d_ws;
  int* ord = (int*)((char*)d_ws + 20480);
  int* rtab = (int*)((char*)d_ws + 21248);

  hipLaunchKernelGGL(init_kernel, dim3(1), dim3(256), 0, stream, t, ktab, ord, rtab);
  hipLaunchKernelGGL(hpass_kernel, dim3(8, 192), dim3(256), 0, stream, x, t, ktab, ord, rtab, out);
  hipLaunchKernelGGL(wpass_kernel, dim3(8, 192), dim3(256), 0, stream, t, ktab, ord, rtab, out);
}

// Round 6
// 101.266 us; speedup vs baseline: 1.9595x; 1.3694x over previous
//
#include <hip/hip_runtime.h>

#define IMG 65536   // 256*256
#define W 256
#define H 256

// d_ws layout:
//   ktab: 20 x 256 floats (truncated, renormalized composed kernels; tap j at [8+j]), bytes [0, 20480)
//   ord : 192 ints at byte 20480 (images sorted by t desc)
//   rtab: 20 ints at byte 21248 (truncated radius per t)

// One block per t-row: block tt independently recomputes base^{*tt} (exact same
// f64 op sequence as the old serial loop -> bit-identical taps), truncates,
// renormalizes, writes its ktab row. Block 0 writes the identity row and sorts.
__global__ __launch_bounds__(256) void init_kernel(const int* __restrict__ t,
                                                   float* __restrict__ ktab,
                                                   int* __restrict__ ord,
                                                   int* __restrict__ rtab) {
  __shared__ double cur[256];
  __shared__ double sc[256];    // prefix-sum scratch
  __shared__ double base[11];
  __shared__ int keys[192];
  __shared__ int sRmax;
  int tid = threadIdx.x;
  int tt = blockIdx.x;          // 0..19
  if (tid == 0) {
    double p[11];
    double s = 0.0;
    for (int i = 0; i < 11; ++i) {
      double xx = (double)(i - 5) * 0.5;       // x / SIGMA, SIGMA=2
      p[i] = exp(-0.5 * xx * xx);
      s += p[i];
    }
    for (int i = 0; i < 11; ++i) base[i] = (double)(float)(p[i] / s);  // match np float32 taps
  }
  __syncthreads();

  if (tt == 0) {
    // identity kernel row (t=0 safety) + rank-sort images by t desc
    ktab[tid] = (tid == 8) ? 1.0f : 0.0f;
    if (tid == 0) rtab[0] = 0;
    if (tid < 192) keys[tid] = min(max(t[tid / 3], 0), 19);
    __syncthreads();
    if (tid < 192) {
      int k = keys[tid];
      int rank = 0;
      for (int j = 0; j < 192; ++j) {
        int kj = keys[j];
        if (kj > k || (kj == k && j < tid)) ++rank;
      }
      ord[rank] = tid;
    }
    return;
  }

  cur[tid] = (tid < 11) ? base[tid] : 0.0;
  __syncthreads();
  for (int step = 2; step <= tt; ++step) {
    int Lprev = 10 * (step - 1) + 1;
    double a = 0.0;
    for (int i = 0; i < 11; ++i) {
      int jj = tid - i;
      if (jj >= 0 && jj < Lprev) a += base[i] * cur[jj];
    }
    __syncthreads();
    cur[tid] = a;
    __syncthreads();
  }
  // parallel inclusive prefix sum of cur -> sc (Hillis-Steele, 8 steps)
  sc[tid] = cur[tid];
  __syncthreads();
#pragma unroll
  for (int off = 1; off < 256; off <<= 1) {
    double tmp = (tid >= off) ? sc[tid - off] : 0.0;
    __syncthreads();
    sc[tid] += tmp;
    __syncthreads();
  }
  if (tid == 0) sRmax = 1;
  __syncthreads();
  // truncation: R = max r in [1,5t] with tail-outside-(r-1) > 1e-5  (monotone)
  int c = 5 * tt;
  double total = sc[255];
  if (tid >= 1 && tid <= c) {
    double Srm1 = sc[c + tid - 1] - sc[c - tid];     // window sum, radius tid-1
    if (total - Srm1 > 1e-5) atomicMax(&sRmax, tid);
  }
  __syncthreads();
  int Rk = sRmax;
  double ksum = sc[c + Rk] - ((c - Rk - 1 >= 0) ? sc[c - Rk - 1] : 0.0);
  double scale = 1.0 / ksum;                         // renormalize kept mass to 1
  if (tid == 0) rtab[tt] = Rk;
  int c0 = c - Rk;
  int Lk = 2 * Rk + 1;
  ktab[tt * 256 + tid] =
      (tid >= 8 && tid < 8 + Lk) ? (float)(cur[tid - 8 + c0] * scale) : 0.0f;
}

// H-pass: conv along h. Block = (32-wide w-tile) x (full 256 rows) of one image.
// LDS tile[256][32] = 32 KB. Each thread: 2 groups of 16 consecutive output rows,
// 16-deep rolling tap window. Interior tap-blocks skip reflect math entirely.
__global__ __launch_bounds__(256, 4) void hpass_kernel(const float* __restrict__ x,
                                                       const int* __restrict__ t,
                                                       const float* __restrict__ ktab,
                                                       const int* __restrict__ ord,
                                                       const int* __restrict__ rtab,
                                                       float* __restrict__ out) {
  __shared__ float tile[H][32];
  int tid = threadIdx.x;
  int img = ord[blockIdx.y];
  int wt = blockIdx.x;                        // 0..7
  int b = img / 3;
  int tv = min(max(t[b], 0), 19);
  int R = rtab[tv];
  int L = 2 * R + 1;
  const float* __restrict__ kt = ktab + tv * 256;   // wave-uniform -> s_load taps
  const float* src = x + (size_t)img * IMG + (wt << 5);
  float* dst = out + (size_t)img * IMG + (wt << 5);
  {
    int c4 = (tid & 7) << 2;
    int r0 = tid >> 3;                        // 0..31
    for (int r = r0; r < H; r += 32) {
      float4 v = *reinterpret_cast<const float4*>(src + r * W + c4);
      *reinterpret_cast<float4*>(&tile[r][c4]) = v;
    }
  }
  __syncthreads();
  int col = tid & 31;
  int rgrp = tid >> 5;                        // 0..7
  int nIter = (L + 30) & ~15;                 // >= L+15, multiple of 16; extra taps are zeros
  for (int g = 0; g < 2; ++g) {
    int h0 = (rgrp << 5) + (g << 4);
    float acc[16];
    float kq[16];
#pragma unroll
    for (int o = 0; o < 16; ++o) { acc[o] = 0.f; kq[o] = 0.f; }
    int pbase = h0 - R;
    for (int jb = 0; jb < nIter; jb += 16) {
      int p0 = pbase + jb;
      if (p0 >= 0 && p0 <= 240) {
        // interior fast path: sequential LDS addresses (offset immediates)
#pragma unroll
        for (int u = 0; u < 16; ++u) {
          kq[u] = kt[jb + u + 8];
          float v = tile[p0 + u][col];
#pragma unroll
          for (int o = 0; o < 16; ++o) acc[o] += kq[(u - o) & 15] * v;
        }
      } else {
#pragma unroll
        for (int u = 0; u < 16; ++u) {
          kq[u] = kt[jb + u + 8];
          int p = p0 + u;
          int rp = 255 - abs(255 - abs(p));   // reflect (single fold valid: |p| <= 510)
          float v = tile[rp][col];
#pragma unroll
          for (int o = 0; o < 16; ++o) acc[o] += kq[(u - o) & 15] * v;
        }
      }
    }
#pragma unroll
    for (int o = 0; o < 16; ++o) dst[(h0 + o) * W + col] = acc[o];
  }
}

// W-pass: conv along w, in-place on out. Block = (32-row band) x (full 256 cols).
// LDS tile[32][256] word-XOR-swizzled so lane=row reads (stride 1 KB) are conflict-free.
__global__ __launch_bounds__(256, 4) void wpass_kernel(const int* __restrict__ t,
                                                       const float* __restrict__ ktab,
                                                       const int* __restrict__ ord,
                                                       const int* __restrict__ rtab,
                                                       float* __restrict__ io) {
  __shared__ float tile[32 * 256];
  int tid = threadIdx.x;
  int img = ord[blockIdx.y];
  int ht = blockIdx.x;                        // 0..7
  int b = img / 3;
  int tv = min(max(t[b], 0), 19);
  int R = rtab[tv];
  int L = 2 * R + 1;
  const float* __restrict__ kt = ktab + tv * 256;
  float* base = io + (size_t)img * IMG + (ht << 5) * W;
  {
    int r = tid >> 3;                         // 0..31
    int c4 = (tid & 7) << 2;
    int sw = r;                               // word-granular swizzle key
    for (int kk = 0; kk < 8; ++kk) {
      int c = c4 + (kk << 5);
      float4 v = *reinterpret_cast<const float4*>(base + r * W + c);
      tile[(r << 8) + ((c + 0) ^ sw)] = v.x;
      tile[(r << 8) + ((c + 1) ^ sw)] = v.y;
      tile[(r << 8) + ((c + 2) ^ sw)] = v.z;
      tile[(r << 8) + ((c + 3) ^ sw)] = v.w;
    }
  }
  __syncthreads();
  int row = tid & 31;
  int wgrp = tid >> 5;                        // 0..7
  int rowbase = row << 8;
  int sw = row;
  int nIter = (L + 30) & ~15;
  for (int g = 0; g < 2; ++g) {
    int w0 = (wgrp << 5) + (g << 4);
    float acc[16];
    float kq[16];
#pragma unroll
    for (int o = 0; o < 16; ++o) { acc[o] = 0.f; kq[o] = 0.f; }
    int pbase = w0 - R;
    for (int jb = 0; jb < nIter; jb += 16) {
      int p0 = pbase + jb;
      if (p0 >= 0 && p0 <= 240) {
#pragma unroll
        for (int u = 0; u < 16; ++u) {
          kq[u] = kt[jb + u + 8];
          float v = tile[rowbase + ((p0 + u) ^ sw)];
#pragma unroll
          for (int o = 0; o < 16; ++o) acc[o] += kq[(u - o) & 15] * v;
        }
      } else {
#pragma unroll
        for (int u = 0; u < 16; ++u) {
          kq[u] = kt[jb + u + 8];
          int p = p0 + u;
          int rp = 255 - abs(255 - abs(p));
          float v = tile[rowbase + (rp ^ sw)];
#pragma unroll
          for (int o = 0; o < 16; ++o) acc[o] += kq[(u - o) & 15] * v;
        }
      }
    }
    float4 v0 = make_float4(acc[0], acc[1], acc[2], acc[3]);
    float4 v1 = make_float4(acc[4], acc[5], acc[6], acc[7]);
    float4 v2 = make_float4(acc[8], acc[9], acc[10], acc[11]);
    float4 v3 = make_float4(acc[12], acc[13], acc[14], acc[15]);
    float* o0 = base + row * W + w0;
    *reinterpret_cast<float4*>(o0 + 0) = v0;
    *reinterpret_cast<float4*>(o0 + 4) = v1;
    *reinterpret_cast<float4*>(o0 + 8) = v2;
    *reinterpret_cast<float4*>(o0 + 12) = v3;
  }
}

extern "C" void kernel_launch(void* const* d_in, const int* in_sizes, int n_in,
                              void* d_out, int out_size, void* d_ws, size_t ws_size,
                              hipStream_t stream) {
  const float* x = (const float*)d_in[0];
  const int* t = (const int*)d_in[1];
  float* out = (float*)d_out;
  float* ktab = (float*)d_ws;
  int* ord = (int*)((char*)d_ws + 20480);
  int* rtab = (int*)((char*)d_ws + 21248);

  hipLaunchKernelGGL(init_kernel, dim3(20), dim3(256), 0, stream, t, ktab, ord, rtab);
  hipLaunchKernelGGL(hpass_kernel, dim3(8, 192), dim3(256), 0, stream, x, t, ktab, ord, rtab, out);
  hipLaunchKernelGGL(wpass_kernel, dim3(8, 192), dim3(256), 0, stream, t, ktab, ord, rtab, out);
}

// Round 7
// 94.988 us; speedup vs baseline: 2.0890x; 1.0661x over previous
//
#include <hip/hip_runtime.h>

#define IMG 65536   // 256*256
#define W 256
#define H 256

// d_ws layout:
//   ktab: 20 x 256 floats (truncated, renormalized composed kernels; tap j at [8+j]), bytes [0, 20480)
//   ord : 192 ints at byte 20480 (images sorted by t desc)
//   rtab: 20 ints at byte 21248 (truncated radius per t)

// One block per t-row: block tt independently recomputes base^{*tt} (exact same
// f64 op sequence as the old serial loop -> bit-identical taps), truncates,
// renormalizes, writes its ktab row. Block 0 writes the identity row and sorts.
__global__ __launch_bounds__(256) void init_kernel(const int* __restrict__ t,
                                                   float* __restrict__ ktab,
                                                   int* __restrict__ ord,
                                                   int* __restrict__ rtab) {
  __shared__ double cur[256];
  __shared__ double sc[256];    // prefix-sum scratch
  __shared__ double base[11];
  __shared__ int keys[192];
  __shared__ int sRmax;
  int tid = threadIdx.x;
  int tt = blockIdx.x;          // 0..19
  if (tid == 0) {
    double p[11];
    double s = 0.0;
    for (int i = 0; i < 11; ++i) {
      double xx = (double)(i - 5) * 0.5;       // x / SIGMA, SIGMA=2
      p[i] = exp(-0.5 * xx * xx);
      s += p[i];
    }
    for (int i = 0; i < 11; ++i) base[i] = (double)(float)(p[i] / s);  // match np float32 taps
  }
  __syncthreads();

  if (tt == 0) {
    // identity kernel row (t=0 safety) + rank-sort images by t desc
    ktab[tid] = (tid == 8) ? 1.0f : 0.0f;
    if (tid == 0) rtab[0] = 0;
    if (tid < 192) keys[tid] = min(max(t[tid / 3], 0), 19);
    __syncthreads();
    if (tid < 192) {
      int k = keys[tid];
      int rank = 0;
      for (int j = 0; j < 192; ++j) {
        int kj = keys[j];
        if (kj > k || (kj == k && j < tid)) ++rank;
      }
      ord[rank] = tid;
    }
    return;
  }

  cur[tid] = (tid < 11) ? base[tid] : 0.0;
  __syncthreads();
  for (int step = 2; step <= tt; ++step) {
    int Lprev = 10 * (step - 1) + 1;
    double a = 0.0;
    for (int i = 0; i < 11; ++i) {
      int jj = tid - i;
      if (jj >= 0 && jj < Lprev) a += base[i] * cur[jj];
    }
    __syncthreads();
    cur[tid] = a;
    __syncthreads();
  }
  // parallel inclusive prefix sum of cur -> sc (Hillis-Steele, 8 steps)
  sc[tid] = cur[tid];
  __syncthreads();
#pragma unroll
  for (int off = 1; off < 256; off <<= 1) {
    double tmp = (tid >= off) ? sc[tid - off] : 0.0;
    __syncthreads();
    sc[tid] += tmp;
    __syncthreads();
  }
  if (tid == 0) sRmax = 1;
  __syncthreads();
  // truncation: R = max r in [1,5t] with tail-outside-(r-1) > 1e-5  (monotone)
  int c = 5 * tt;
  double total = sc[255];
  if (tid >= 1 && tid <= c) {
    double Srm1 = sc[c + tid - 1] - sc[c - tid];     // window sum, radius tid-1
    if (total - Srm1 > 1e-5) atomicMax(&sRmax, tid);
  }
  __syncthreads();
  int Rk = sRmax;
  double ksum = sc[c + Rk] - ((c - Rk - 1 >= 0) ? sc[c - Rk - 1] : 0.0);
  double scale = 1.0 / ksum;                         // renormalize kept mass to 1
  if (tid == 0) rtab[tt] = Rk;
  int c0 = c - Rk;
  int Lk = 2 * Rk + 1;
  ktab[tt * 256 + tid] =
      (tid >= 8 && tid < 8 + Lk) ? (float)(cur[tid - 8 + c0] * scale) : 0.0f;
}

// H-pass: conv along h. Block = (32-wide w-tile) x (full 256 rows) of one image.
// LDS tile[256][32] = 32 KB -> 5 blocks/CU. Block-uniform values scalarized via
// readfirstlane so taps become s_load and loop bounds are SALU.
__global__ __launch_bounds__(256, 5) void hpass_kernel(const float* __restrict__ x,
                                                       const int* __restrict__ t,
                                                       const float* __restrict__ ktab,
                                                       const int* __restrict__ ord,
                                                       const int* __restrict__ rtab,
                                                       float* __restrict__ out) {
  __shared__ float tile[H][32];
  int tid = threadIdx.x;
  int img = __builtin_amdgcn_readfirstlane(ord[blockIdx.y]);
  int wt = blockIdx.x;                        // 0..7
  int b = img / 3;
  int tv = __builtin_amdgcn_readfirstlane(min(max(t[b], 0), 19));
  int R = __builtin_amdgcn_readfirstlane(rtab[tv]);
  int L = 2 * R + 1;
  const float* __restrict__ kt = ktab + tv * 256;   // SGPR base -> s_load taps
  const float* src = x + (size_t)img * IMG + (wt << 5);
  float* dst = out + (size_t)img * IMG + (wt << 5);
  {
    int c4 = (tid & 7) << 2;
    int r0 = tid >> 3;                        // 0..31
#pragma unroll
    for (int i = 0; i < 8; ++i) {
      int r = r0 + (i << 5);
      float4 v = *reinterpret_cast<const float4*>(src + r * W + c4);
      *reinterpret_cast<float4*>(&tile[r][c4]) = v;
    }
  }
  __syncthreads();
  int col = tid & 31;
  int rgrp = tid >> 5;                        // 0..7
  int nIter = (L + 30) & ~15;                 // >= L+15, multiple of 16; extra taps are zeros
  for (int g = 0; g < 2; ++g) {
    int h0 = (rgrp << 5) + (g << 4);
    float acc[16];
    float kq[16];
#pragma unroll
    for (int o = 0; o < 16; ++o) { acc[o] = 0.f; kq[o] = 0.f; }
    int pbase = h0 - R;
    for (int jb = 0; jb < nIter; jb += 16) {
      int p0 = pbase + jb;
      if (p0 >= 0 && p0 <= 240) {
        // interior fast path: sequential LDS addresses (offset immediates)
#pragma unroll
        for (int u = 0; u < 16; ++u) {
          kq[u] = kt[jb + u + 8];
          float v = tile[p0 + u][col];
#pragma unroll
          for (int o = 0; o < 16; ++o) acc[o] += kq[(u - o) & 15] * v;
        }
      } else {
#pragma unroll
        for (int u = 0; u < 16; ++u) {
          kq[u] = kt[jb + u + 8];
          int p = p0 + u;
          int rp = 255 - abs(255 - abs(p));   // reflect (single fold valid: |p| <= 510)
          float v = tile[rp][col];
#pragma unroll
          for (int o = 0; o < 16; ++o) acc[o] += kq[(u - o) & 15] * v;
        }
      }
    }
#pragma unroll
    for (int o = 0; o < 16; ++o) dst[(h0 + o) * W + col] = acc[o];
  }
}

// W-pass: conv along w, in-place on out. Block = (32-row band) x (full 256 cols).
// LDS tile[32][256] word-XOR-swizzled so lane=row reads (stride 1 KB) are conflict-free.
__global__ __launch_bounds__(256, 5) void wpass_kernel(const int* __restrict__ t,
                                                       const float* __restrict__ ktab,
                                                       const int* __restrict__ ord,
                                                       const int* __restrict__ rtab,
                                                       float* __restrict__ io) {
  __shared__ float tile[32 * 256];
  int tid = threadIdx.x;
  int img = __builtin_amdgcn_readfirstlane(ord[blockIdx.y]);
  int ht = blockIdx.x;                        // 0..7
  int b = img / 3;
  int tv = __builtin_amdgcn_readfirstlane(min(max(t[b], 0), 19));
  int R = __builtin_amdgcn_readfirstlane(rtab[tv]);
  int L = 2 * R + 1;
  const float* __restrict__ kt = ktab + tv * 256;   // SGPR base -> s_load taps
  float* base = io + (size_t)img * IMG + (ht << 5) * W;
  {
    int r = tid >> 3;                         // 0..31
    int c4 = (tid & 7) << 2;
    int sw = r;                               // word-granular swizzle key
#pragma unroll
    for (int kk = 0; kk < 8; ++kk) {
      int c = c4 + (kk << 5);
      float4 v = *reinterpret_cast<const float4*>(base + r * W + c);
      tile[(r << 8) + ((c + 0) ^ sw)] = v.x;
      tile[(r << 8) + ((c + 1) ^ sw)] = v.y;
      tile[(r << 8) + ((c + 2) ^ sw)] = v.z;
      tile[(r << 8) + ((c + 3) ^ sw)] = v.w;
    }
  }
  __syncthreads();
  int row = tid & 31;
  int wgrp = tid >> 5;                        // 0..7
  int rowbase = row << 8;
  int sw = row;
  int nIter = (L + 30) & ~15;
  for (int g = 0; g < 2; ++g) {
    int w0 = (wgrp << 5) + (g << 4);
    float acc[16];
    float kq[16];
#pragma unroll
    for (int o = 0; o < 16; ++o) { acc[o] = 0.f; kq[o] = 0.f; }
    int pbase = w0 - R;
    for (int jb = 0; jb < nIter; jb += 16) {
      int p0 = pbase + jb;
      if (p0 >= 0 && p0 <= 240) {
#pragma unroll
        for (int u = 0; u < 16; ++u) {
          kq[u] = kt[jb + u + 8];
          float v = tile[rowbase + ((p0 + u) ^ sw)];
#pragma unroll
          for (int o = 0; o < 16; ++o) acc[o] += kq[(u - o) & 15] * v;
        }
      } else {
#pragma unroll
        for (int u = 0; u < 16; ++u) {
          kq[u] = kt[jb + u + 8];
          int p = p0 + u;
          int rp = 255 - abs(255 - abs(p));
          float v = tile[rowbase + (rp ^ sw)];
#pragma unroll
          for (int o = 0; o < 16; ++o) acc[o] += kq[(u - o) & 15] * v;
        }
      }
    }
    float4 v0 = make_float4(acc[0], acc[1], acc[2], acc[3]);
    float4 v1 = make_float4(acc[4], acc[5], acc[6], acc[7]);
    float4 v2 = make_float4(acc[8], acc[9], acc[10], acc[11]);
    float4 v3 = make_float4(acc[12], acc[13], acc[14], acc[15]);
    float* o0 = base + row * W + w0;
    *reinterpret_cast<float4*>(o0 + 0) = v0;
    *reinterpret_cast<float4*>(o0 + 4) = v1;
    *reinterpret_cast<float4*>(o0 + 8) = v2;
    *reinterpret_cast<float4*>(o0 + 12) = v3;
  }
}

extern "C" void kernel_launch(void* const* d_in, const int* in_sizes, int n_in,
                              void* d_out, int out_size, void* d_ws, size_t ws_size,
                              hipStream_t stream) {
  const float* x = (const float*)d_in[0];
  const int* t = (const int*)d_in[1];
  float* out = (float*)d_out;
  float* ktab = (float*)d_ws;
  int* ord = (int*)((char*)d_ws + 20480);
  int* rtab = (int*)((char*)d_ws + 21248);

  hipLaunchKernelGGL(init_kernel, dim3(20), dim3(256), 0, stream, t, ktab, ord, rtab);
  hipLaunchKernelGGL(hpass_kernel, dim3(8, 192), dim3(256), 0, stream, x, t, ktab, ord, rtab, out);
  hipLaunchKernelGGL(wpass_kernel, dim3(8, 192), dim3(256), 0, stream, t, ktab, ord, rtab, out);
}